// Round 5
// baseline (242.774 us; speedup 1.0000x reference)
//
#include <hip/hip_runtime.h>
#include <hip/hip_bf16.h>

#define BATCH 4
#define SEQ 2048
#define DM 512
#define NH 8
#define DH 64
#define WINDOW 256
#define NEGINF (-1e30f)
#define C_SCALE 0.18033688f   /* 0.125 * 1/ln2 : scores -> log2 domain */
#define THR2 11.5415603f      /* defer-max threshold 8 * 1/ln2 */

typedef __attribute__((ext_vector_type(8))) short bf16x8;
typedef __attribute__((ext_vector_type(4))) float f32x4;

__device__ __forceinline__ unsigned short f2bf(float f) {
    __hip_bfloat16 h = __float2bfloat16(f);
    union { __hip_bfloat16 h; unsigned short u; } cv; cv.h = h; return cv.u;
}
__device__ __forceinline__ unsigned int pack2(float a, float b) {
    return (unsigned int)f2bf(a) | ((unsigned int)f2bf(b) << 16);
}

// 64-col bf16 tiles: 128-byte rows, XOR swizzle on byte bits 4-6
__device__ __forceinline__ int swz128(int row, int byte_in_row) {
    return row * 128 + (byte_in_row ^ ((row & 7) << 4));
}

#define MFMA(a, b, c) __builtin_amdgcn_mfma_f32_16x16x32_bf16(a, b, c, 0, 0, 0)

// ---------------- fp32 -> bf16 converters (one-time) ----------------
__global__ __launch_bounds__(256) void cvt8(const float* __restrict__ in,
                                            unsigned short* __restrict__ out, int n8) {
    int i = blockIdx.x * 256 + threadIdx.x;
    if (i >= n8) return;
    const float4* p = (const float4*)in + 2 * (size_t)i;
    float4 a = p[0], b = p[1];
    union { unsigned short s[8]; uint4 v; } u;
    u.s[0] = f2bf(a.x); u.s[1] = f2bf(a.y); u.s[2] = f2bf(a.z); u.s[3] = f2bf(a.w);
    u.s[4] = f2bf(b.x); u.s[5] = f2bf(b.y); u.s[6] = f2bf(b.z); u.s[7] = f2bf(b.w);
    *reinterpret_cast<uint4*>(out + 8 * (size_t)i) = u.v;
}

__global__ __launch_bounds__(256) void cvt8_w(
    const float* __restrict__ W0, const float* __restrict__ W1,
    const float* __restrict__ W2, const float* __restrict__ W3,
    unsigned short* __restrict__ out, int n8) {
    const float* in = (blockIdx.y == 0) ? W0 : (blockIdx.y == 1) ? W1
                    : (blockIdx.y == 2) ? W2 : W3;
    unsigned short* o = out + (size_t)blockIdx.y * n8 * 8;
    int i = blockIdx.x * 256 + threadIdx.x;
    if (i >= n8) return;
    const float4* p = (const float4*)in + 2 * (size_t)i;
    float4 a = p[0], b = p[1];
    union { unsigned short s[8]; uint4 v; } u;
    u.s[0] = f2bf(a.x); u.s[1] = f2bf(a.y); u.s[2] = f2bf(a.z); u.s[3] = f2bf(a.w);
    u.s[4] = f2bf(b.x); u.s[5] = f2bf(b.y); u.s[6] = f2bf(b.z); u.s[7] = f2bf(b.w);
    *reinterpret_cast<uint4*>(o + 8 * (size_t)i) = u.v;
}

// ---------------------------------------------------------------------------
// GEMM: C[M,N] = A[M,K] @ W[N,K]^T, all-bf16 inputs, 128x128 tile, BK=64,
// 4 waves, register-prefetched staging. blockIdx.z picks weight slice.
// ---------------------------------------------------------------------------
template<bool OUT_BF16>
__global__ __launch_bounds__(256) void gemm_mfma(
    const unsigned short* __restrict__ A,
    const unsigned short* __restrict__ Wbase,
    void* __restrict__ C0, void* __restrict__ C1, void* __restrict__ C2,
    int M, int N, int K)
{
    const unsigned short* W = Wbase + (size_t)blockIdx.z * N * K;
    void* C = (blockIdx.z == 0) ? C0 : (blockIdx.z == 1) ? C1 : C2;

    __shared__ unsigned short As[128 * 64];
    __shared__ unsigned short Ws[128 * 64];

    const int tid  = threadIdx.x;
    const int m0   = blockIdx.x * 128;
    const int n0   = blockIdx.y * 128;
    const int lane = tid & 63;
    const int wv   = tid >> 6;
    const int wm   = wv >> 1, wn = wv & 1;
    const int g    = lane >> 4;
    const int lr   = lane & 15;
    const int r0   = tid >> 2;
    const int cgrp = tid & 3;

    f32x4 acc[4][4];
#pragma unroll
    for (int i = 0; i < 4; ++i)
#pragma unroll
        for (int j = 0; j < 4; ++j) { f32x4 z = {0.f,0.f,0.f,0.f}; acc[i][j] = z; }

    uint4 pa[2][2], pw[2][2];
    auto issue = [&](int k0) {
#pragma unroll
        for (int rr = 0; rr < 2; ++rr) {
            const unsigned short* sa = A + (size_t)(m0 + r0 + 64 * rr) * K + k0 + cgrp * 16;
            pa[rr][0] = *reinterpret_cast<const uint4*>(sa);
            pa[rr][1] = *reinterpret_cast<const uint4*>(sa + 8);
            const unsigned short* sw = W + (size_t)(n0 + r0 + 64 * rr) * K + k0 + cgrp * 16;
            pw[rr][0] = *reinterpret_cast<const uint4*>(sw);
            pw[rr][1] = *reinterpret_cast<const uint4*>(sw + 8);
        }
    };
    issue(0);

    for (int k0 = 0; k0 < K; k0 += 64) {
        __syncthreads();
#pragma unroll
        for (int rr = 0; rr < 2; ++rr) {
            const int r = r0 + 64 * rr;
            *reinterpret_cast<uint4*>((char*)As + swz128(r, cgrp * 32))      = pa[rr][0];
            *reinterpret_cast<uint4*>((char*)As + swz128(r, cgrp * 32 + 16)) = pa[rr][1];
            *reinterpret_cast<uint4*>((char*)Ws + swz128(r, cgrp * 32))      = pw[rr][0];
            *reinterpret_cast<uint4*>((char*)Ws + swz128(r, cgrp * 32 + 16)) = pw[rr][1];
        }
        __syncthreads();
        if (k0 + 64 < K) issue(k0 + 64);

#pragma unroll
        for (int ks = 0; ks < 2; ++ks) {
            bf16x8 af[4], bfr[4];
#pragma unroll
            for (int i = 0; i < 4; ++i)
                af[i] = *reinterpret_cast<const bf16x8*>(
                    (char*)As + swz128(64 * wm + 16 * i + lr, 64 * ks + 16 * g));
#pragma unroll
            for (int j = 0; j < 4; ++j)
                bfr[j] = *reinterpret_cast<const bf16x8*>(
                    (char*)Ws + swz128(64 * wn + 16 * j + lr, 64 * ks + 16 * g));
#pragma unroll
            for (int i = 0; i < 4; ++i)
#pragma unroll
                for (int j = 0; j < 4; ++j)
                    acc[i][j] = MFMA(af[i], bfr[j], acc[i][j]);
        }
    }

#pragma unroll
    for (int i = 0; i < 4; ++i)
#pragma unroll
        for (int j = 0; j < 4; ++j) {
            const int col = n0 + 64 * wn + 16 * j + lr;
#pragma unroll
            for (int r = 0; r < 4; ++r) {
                const int row = m0 + 64 * wm + 16 * i + 4 * g + r;
                if constexpr (OUT_BF16)
                    ((unsigned short*)C)[(size_t)row * N + col] = f2bf(acc[i][j][r]);
                else
                    ((float*)C)[(size_t)row * N + col] = acc[i][j][r];
            }
        }
}

// ---------------------------------------------------------------------------
// Flash attention, bf16 MFMA. Swapped QK^T (acc = C[kv][q]) -> lane-local
// softmax; P redistributed to PV A-fragments via a verified 4-shuffle
// permutation schedule (no P LDS); double-buffered K/V LDS, one barrier/tile.
// ---------------------------------------------------------------------------
__global__ __launch_bounds__(256) void attn_mfma(
    const unsigned short* __restrict__ Q, const unsigned short* __restrict__ K,
    const unsigned short* __restrict__ V, const int* __restrict__ amask,
    unsigned short* __restrict__ AO)
{
    __shared__ unsigned short Ks[2][64 * 64];   // [kv][d] swizzled
    __shared__ unsigned short Vt[2][64 * 64];   // [d][kv] swizzled
    __shared__ unsigned long long Msk[2];

    const int tid = threadIdx.x;
    const int qb  = (int)gridDim.x - 1 - (int)blockIdx.x;   // big blocks first
    const int n0  = qb * 64;
    const int bh  = blockIdx.y;
    const int b = bh >> 3, h = bh & 7;

    const int lane = tid & 63;
    const int wv   = tid >> 6;
    const int g    = lane >> 4;
    const int lr   = lane & 15;

    // Q fragment (B-operand): lane holds q row n0+16wv+lr, d elems 8g..8g+7 (+32)
    bf16x8 qf[2];
    {
        const unsigned short* qp =
            Q + (size_t)(b * SEQ + n0 + 16 * wv + lr) * DM + h * DH + 8 * g;
        qf[0] = *reinterpret_cast<const bf16x8*>(qp);
        qf[1] = *reinterpret_cast<const bf16x8*>(qp + 32);
    }

    f32x4 o[4];
#pragma unroll
    for (int j = 0; j < 4; ++j) { f32x4 z = {0.f,0.f,0.f,0.f}; o[j] = z; }
    float m_run2 = NEGINF;   // running max, log2 units, for q = lr
    float l_run  = 0.f;

    int ntiles = (n0 + 63 + WINDOW - 1) / 64 + 1;
    if (ntiles > SEQ / 64) ntiles = SEQ / 64;

    const int r_st = tid & 63;
    const int half = tid >> 6;
    const unsigned short* kpt = K + (size_t)(b * SEQ + r_st) * DM + h * DH + 16 * half;
    const unsigned short* vpt = V + (size_t)(b * SEQ + r_st) * DM + h * DH + 16 * half;
    const int* amp = amask + (size_t)b * SEQ + r_st;

    uint4 kr0, kr1, vr0, vr1; int mr = 1;
    auto issue = [&](int tt) {
        const unsigned short* kp = kpt + (size_t)tt * 64 * DM;
        kr0 = *reinterpret_cast<const uint4*>(kp);
        kr1 = *reinterpret_cast<const uint4*>(kp + 8);
        const unsigned short* vp = vpt + (size_t)tt * 64 * DM;
        vr0 = *reinterpret_cast<const uint4*>(vp);
        vr1 = *reinterpret_cast<const uint4*>(vp + 8);
        mr = amp[tt * 64];
    };
    auto writeKV = [&](int buf) {
        *reinterpret_cast<uint4*>((char*)Ks[buf] + swz128(r_st, 32 * half))      = kr0;
        *reinterpret_cast<uint4*>((char*)Ks[buf] + swz128(r_st, 32 * half + 16)) = kr1;
        union { uint4 v[2]; unsigned short s[16]; } tv;
        tv.v[0] = vr0; tv.v[1] = vr1;
#pragma unroll
        for (int j = 0; j < 16; ++j)
            *(unsigned short*)((char*)Vt[buf] + swz128(16 * half + j, 2 * r_st)) = tv.s[j];
        unsigned long long good = __ballot(mr != 0);
        if (tid == 0) Msk[buf] = good;
    };

    issue(0);
    writeKV(0);

    const int qg   = n0 + 16 * wv + lr;   // this lane's q row
    const int qmin = n0 + 16 * wv;

    for (int t = 0; t < ntiles; ++t) {
        const int cur = t & 1;
        const int kv0 = t * 64;
        __syncthreads();
        if (t + 1 < ntiles) issue(t + 1);

        if (kv0 <= qmin + 15 + WINDOW - 1) {   // wave has in-band rows
            const unsigned long long mw = Msk[cur];
            const bool fullband =
                ((kv0 + 63 - qmin) <= (WINDOW - 1)) && (mw == ~0ULL);

            // ---- S = K Q^T : acc rows = kv (16f+4g+r), cols = q (= lr) ----
            f32x4 s[4];
#pragma unroll
            for (int f = 0; f < 4; ++f) {
                bf16x8 kf0 = *reinterpret_cast<const bf16x8*>(
                    (char*)Ks[cur] + swz128(16 * f + lr, 16 * g));
                bf16x8 kf1 = *reinterpret_cast<const bf16x8*>(
                    (char*)Ks[cur] + swz128(16 * f + lr, 64 + 16 * g));
                f32x4 z = {0.f,0.f,0.f,0.f};
                z = MFMA(kf0, qf[0], z);
                z = MFMA(kf1, qf[1], z);
                s[f] = z;
            }

            // ---- mask (boundary tiles only) ----
            if (!fullband) {
                const int lim = qg + (WINDOW - 1) - kv0;   // kvl <= lim allowed
#pragma unroll
                for (int f = 0; f < 4; ++f)
#pragma unroll
                    for (int r = 0; r < 4; ++r) {
                        const int kvl = 16 * f + 4 * g + r;
                        const bool ok = (kvl <= lim) && ((mw >> kvl) & 1ULL);
                        s[f][r] = ok ? s[f][r] : NEGINF;
                    }
            }

            // ---- lane-local row max over 16 kv + cross-g reduce ----
            float tmax;
            {
                float a0 = fmaxf(fmaxf(s[0][0], s[0][1]), fmaxf(s[0][2], s[0][3]));
                float a1 = fmaxf(fmaxf(s[1][0], s[1][1]), fmaxf(s[1][2], s[1][3]));
                float a2 = fmaxf(fmaxf(s[2][0], s[2][1]), fmaxf(s[2][2], s[2][3]));
                float a3 = fmaxf(fmaxf(s[3][0], s[3][1]), fmaxf(s[3][2], s[3][3]));
                tmax = fmaxf(fmaxf(a0, a1), fmaxf(a2, a3));
            }
            tmax = fmaxf(tmax, __shfl_xor(tmax, 16));
            tmax = fmaxf(tmax, __shfl_xor(tmax, 32));
            const float tm2 = tmax * C_SCALE;

            // ---- defer-max rescale ----
            if (!__all(tm2 - m_run2 <= THR2)) {
                const float mn = fmaxf(m_run2, tm2);
                const float sc = exp2f(m_run2 - mn);
                m_run2 = mn;
                l_run *= sc;
#pragma unroll
                for (int r = 0; r < 4; ++r) {
                    const float scq = __shfl(sc, (lane & 48) | (4 * g + r));
                    o[0][r] *= scq; o[1][r] *= scq; o[2][r] *= scq; o[3][r] *= scq;
                }
            }

            // ---- P = exp2(s*C - m), sum, pack to bf16 pairs ----
            float ls = 0.f;
            unsigned int pk0[4], pk1[4];
#pragma unroll
            for (int f = 0; f < 4; ++f) {
                const float p0 = exp2f(fmaf(s[f][0], C_SCALE, -m_run2));
                const float p1 = exp2f(fmaf(s[f][1], C_SCALE, -m_run2));
                const float p2 = exp2f(fmaf(s[f][2], C_SCALE, -m_run2));
                const float p3 = exp2f(fmaf(s[f][3], C_SCALE, -m_run2));
                ls += (p0 + p1) + (p2 + p3);
                pk0[f] = pack2(p0, p1);
                pk1[f] = pack2(p2, p3);
            }
            ls += __shfl_xor(ls, 16);
            ls += __shfl_xor(ls, 32);
            l_run += ls;

            // ---- O += P V : A-frag via 4-shuffle permutation schedule ----
            // Dest lane (g,lr), slot w=2c+h needs P[q=lr][kv=32ks+8g+2w(,+1)]
            //   = pair (F=g>>1, h) held at source lane 16*(2(g&1)+c)+lr.
            // Call u: every lane OFFERS pk[u&1][2ks + ((u>>1)^(g&1))] and
            // PULLS from lane 16*(2(g&1)+((u>>1)^(g>>1)))+lr; the received
            // word is slot u with bit1 flipped by (g>>1).  (each source word
            // consumed exactly once per call — verified permutation)
#pragma unroll
            for (int ks = 0; ks < 2; ++ks) {
                unsigned int rcv[4];
#pragma unroll
                for (int u = 0; u < 4; ++u) {
                    const int uc = u >> 1;
                    const unsigned int v0 = (g & 1) ? pk0[2 * ks + (uc ^ 1)]
                                                    : pk0[2 * ks + uc];
                    const unsigned int v1 = (g & 1) ? pk1[2 * ks + (uc ^ 1)]
                                                    : pk1[2 * ks + uc];
                    const unsigned int val = (u & 1) ? v1 : v0;
                    const int src = 16 * (2 * (g & 1) + (uc ^ (g >> 1))) + lr;
                    rcv[u] = (unsigned int)__shfl((int)val, src);
                }
                const bool gh = (g & 2) != 0;
                union { unsigned int w[4]; bf16x8 v; } af;
                af.w[0] = gh ? rcv[2] : rcv[0];
                af.w[1] = gh ? rcv[3] : rcv[1];
                af.w[2] = gh ? rcv[0] : rcv[2];
                af.w[3] = gh ? rcv[1] : rcv[3];
#pragma unroll
                for (int j = 0; j < 4; ++j) {
                    bf16x8 vf = *reinterpret_cast<const bf16x8*>(
                        (char*)Vt[cur] + swz128(16 * j + lr, 64 * ks + 16 * g));
                    o[j] = MFMA(af.v, vf, o[j]);
                }
            }
        }

        if (t + 1 < ntiles) writeKV((t + 1) & 1);   // loads had full compute to land
    }

    // ---- normalize + store (o rows: q = 4g+r, cols: d = 16j+lr) ----
    const float inv = 1.f / l_run;   // for q = lr
#pragma unroll
    for (int r = 0; r < 4; ++r) {
        const float invq = __shfl(inv, (lane & 48) | (4 * g + r));
        const int row = n0 + 16 * wv + 4 * g + r;
#pragma unroll
        for (int j = 0; j < 4; ++j) {
            const int col = h * DH + 16 * j + lr;
            AO[(size_t)(b * SEQ + row) * DM + col] = f2bf(o[j][r] * invq);
        }
    }
}

extern "C" void kernel_launch(void* const* d_in, const int* in_sizes, int n_in,
                              void* d_out, int out_size, void* d_ws, size_t ws_size,
                              hipStream_t stream) {
    const float* hs    = (const float*)d_in[0];
    const int*   amask = (const int*)  d_in[1];
    const float* Wq    = (const float*)d_in[2];
    const float* Wk    = (const float*)d_in[3];
    const float* Wv    = (const float*)d_in[4];
    const float* Wo    = (const float*)d_in[5];
    float* out = (float*)d_out;

    const size_t tok = (size_t)BATCH * SEQ * DM;
    const size_t wsz = (size_t)DM * DM;
    unsigned short* hsb = (unsigned short*)d_ws;
    unsigned short* Qb  = hsb + tok;
    unsigned short* Kb  = Qb + tok;
    unsigned short* Vb  = Kb + tok;
    unsigned short* AOb = Vb + tok;
    unsigned short* Wb  = AOb + tok;

    const int M = BATCH * SEQ;

    cvt8<<<(int)(tok / 8 / 256), 256, 0, stream>>>(hs, hsb, (int)(tok / 8));
    cvt8_w<<<dim3((int)(wsz / 8 / 256), 4), 256, 0, stream>>>(
        Wq, Wk, Wv, Wo, Wb, (int)(wsz / 8));

    dim3 gQKV(M / 128, DM / 128, 3);
    gemm_mfma<true><<<gQKV, 256, 0, stream>>>(hsb, Wb, Qb, Kb, Vb, M, DM, DM);

    dim3 gAttn(SEQ / 64, BATCH * NH);
    attn_mfma<<<gAttn, 256, 0, stream>>>(Qb, Kb, Vb, amask, AOb);

    dim3 gOut(M / 128, DM / 128, 1);
    gemm_mfma<false><<<gOut, 256, 0, stream>>>(
        AOb, Wb + 3 * wsz, out, out, out, M, DM, DM);
}

// Round 6
// 181.016 us; speedup vs baseline: 1.3412x; 1.3412x over previous
//
#include <hip/hip_runtime.h>
#include <hip/hip_bf16.h>

#define BATCH 4
#define SEQ 2048
#define DM 512
#define NH 8
#define DH 64
#define WINDOW 256
#define NEGINF (-1e30f)
#define C_SCALE 0.18033688f   /* 0.125 * 1/ln2 : scores -> log2 domain */
#define THR2 11.5415603f      /* defer-max threshold 8 * 1/ln2 */

typedef __attribute__((ext_vector_type(8)))  short bf16x8;
typedef __attribute__((ext_vector_type(4)))  float f32x4;
typedef __attribute__((ext_vector_type(16))) float f32x16;

__device__ __forceinline__ unsigned short f2bf(float f) {
    __hip_bfloat16 h = __float2bfloat16(f);
    union { __hip_bfloat16 h; unsigned short u; } cv; cv.h = h; return cv.u;
}

// 64-col bf16 tiles: 128-byte rows, XOR swizzle on byte bits 4-6
__device__ __forceinline__ int swz128(int row, int byte_in_row) {
    return row * 128 + (byte_in_row ^ ((row & 7) << 4));
}

#define MFMA(a, b, c)   __builtin_amdgcn_mfma_f32_16x16x32_bf16(a, b, c, 0, 0, 0)
#define MFMA32(a, b, c) __builtin_amdgcn_mfma_f32_32x32x16_bf16(a, b, c, 0, 0, 0)

// ---------------- fp32 -> bf16 converters (one-time) ----------------
__global__ __launch_bounds__(256) void cvt8(const float* __restrict__ in,
                                            unsigned short* __restrict__ out, int n8) {
    int i = blockIdx.x * 256 + threadIdx.x;
    if (i >= n8) return;
    const float4* p = (const float4*)in + 2 * (size_t)i;
    float4 a = p[0], b = p[1];
    union { unsigned short s[8]; uint4 v; } u;
    u.s[0] = f2bf(a.x); u.s[1] = f2bf(a.y); u.s[2] = f2bf(a.z); u.s[3] = f2bf(a.w);
    u.s[4] = f2bf(b.x); u.s[5] = f2bf(b.y); u.s[6] = f2bf(b.z); u.s[7] = f2bf(b.w);
    *reinterpret_cast<uint4*>(out + 8 * (size_t)i) = u.v;
}

__global__ __launch_bounds__(256) void cvt8_w(
    const float* __restrict__ W0, const float* __restrict__ W1,
    const float* __restrict__ W2, const float* __restrict__ W3,
    unsigned short* __restrict__ out, int n8) {
    const float* in = (blockIdx.y == 0) ? W0 : (blockIdx.y == 1) ? W1
                    : (blockIdx.y == 2) ? W2 : W3;
    unsigned short* o = out + (size_t)blockIdx.y * n8 * 8;
    int i = blockIdx.x * 256 + threadIdx.x;
    if (i >= n8) return;
    const float4* p = (const float4*)in + 2 * (size_t)i;
    float4 a = p[0], b = p[1];
    union { unsigned short s[8]; uint4 v; } u;
    u.s[0] = f2bf(a.x); u.s[1] = f2bf(a.y); u.s[2] = f2bf(a.z); u.s[3] = f2bf(a.w);
    u.s[4] = f2bf(b.x); u.s[5] = f2bf(b.y); u.s[6] = f2bf(b.z); u.s[7] = f2bf(b.w);
    *reinterpret_cast<uint4*>(o + 8 * (size_t)i) = u.v;
}

// ---------------------------------------------------------------------------
// GEMM: C[M,N] = A[M,K] @ W[N,K]^T, all-bf16 inputs, 128x128 tile, BK=64,
// 4 waves, register-prefetched staging. blockIdx.z picks weight slice.
// ---------------------------------------------------------------------------
template<bool OUT_BF16>
__global__ __launch_bounds__(256) void gemm_mfma(
    const unsigned short* __restrict__ A,
    const unsigned short* __restrict__ Wbase,
    void* __restrict__ C0, void* __restrict__ C1, void* __restrict__ C2,
    int M, int N, int K)
{
    const unsigned short* W = Wbase + (size_t)blockIdx.z * N * K;
    void* C = (blockIdx.z == 0) ? C0 : (blockIdx.z == 1) ? C1 : C2;

    __shared__ unsigned short As[128 * 64];
    __shared__ unsigned short Ws[128 * 64];

    const int tid  = threadIdx.x;
    const int m0   = blockIdx.x * 128;
    const int n0   = blockIdx.y * 128;
    const int lane = tid & 63;
    const int wv   = tid >> 6;
    const int wm   = wv >> 1, wn = wv & 1;
    const int g    = lane >> 4;
    const int lr   = lane & 15;
    const int r0   = tid >> 2;
    const int cgrp = tid & 3;

    f32x4 acc[4][4];
#pragma unroll
    for (int i = 0; i < 4; ++i)
#pragma unroll
        for (int j = 0; j < 4; ++j) { f32x4 z = {0.f,0.f,0.f,0.f}; acc[i][j] = z; }

    uint4 pa[2][2], pw[2][2];
    auto issue = [&](int k0) {
#pragma unroll
        for (int rr = 0; rr < 2; ++rr) {
            const unsigned short* sa = A + (size_t)(m0 + r0 + 64 * rr) * K + k0 + cgrp * 16;
            pa[rr][0] = *reinterpret_cast<const uint4*>(sa);
            pa[rr][1] = *reinterpret_cast<const uint4*>(sa + 8);
            const unsigned short* sw = W + (size_t)(n0 + r0 + 64 * rr) * K + k0 + cgrp * 16;
            pw[rr][0] = *reinterpret_cast<const uint4*>(sw);
            pw[rr][1] = *reinterpret_cast<const uint4*>(sw + 8);
        }
    };
    issue(0);

    for (int k0 = 0; k0 < K; k0 += 64) {
        __syncthreads();
#pragma unroll
        for (int rr = 0; rr < 2; ++rr) {
            const int r = r0 + 64 * rr;
            *reinterpret_cast<uint4*>((char*)As + swz128(r, cgrp * 32))      = pa[rr][0];
            *reinterpret_cast<uint4*>((char*)As + swz128(r, cgrp * 32 + 16)) = pa[rr][1];
            *reinterpret_cast<uint4*>((char*)Ws + swz128(r, cgrp * 32))      = pw[rr][0];
            *reinterpret_cast<uint4*>((char*)Ws + swz128(r, cgrp * 32 + 16)) = pw[rr][1];
        }
        __syncthreads();
        if (k0 + 64 < K) issue(k0 + 64);

#pragma unroll
        for (int ks = 0; ks < 2; ++ks) {
            bf16x8 af[4], bfr[4];
#pragma unroll
            for (int i = 0; i < 4; ++i)
                af[i] = *reinterpret_cast<const bf16x8*>(
                    (char*)As + swz128(64 * wm + 16 * i + lr, 64 * ks + 16 * g));
#pragma unroll
            for (int j = 0; j < 4; ++j)
                bfr[j] = *reinterpret_cast<const bf16x8*>(
                    (char*)Ws + swz128(64 * wn + 16 * j + lr, 64 * ks + 16 * g));
#pragma unroll
            for (int i = 0; i < 4; ++i)
#pragma unroll
                for (int j = 0; j < 4; ++j)
                    acc[i][j] = MFMA(af[i], bfr[j], acc[i][j]);
        }
    }

#pragma unroll
    for (int i = 0; i < 4; ++i)
#pragma unroll
        for (int j = 0; j < 4; ++j) {
            const int col = n0 + 64 * wn + 16 * j + lr;
#pragma unroll
            for (int r = 0; r < 4; ++r) {
                const int row = m0 + 64 * wm + 16 * i + 4 * g + r;
                if constexpr (OUT_BF16)
                    ((unsigned short*)C)[(size_t)row * N + col] = f2bf(acc[i][j][r]);
                else
                    ((float*)C)[(size_t)row * N + col] = acc[i][j][r];
            }
        }
}

// ---------------------------------------------------------------------------
// Flash attention, 32x32x16 bf16 MFMA, swapped operands.
//   S   = mfma(K-frag, Q-frag)  -> C[kv][q], q = lane&31 (lane-local softmax)
//   O^T = mfma(V^T-frag, P-frag)-> C[d][q],  q = lane&31 (no-shuffle rescale)
// P rebuilt in-register: 16 v_cvt_pk_bf16_f32 + 8 v_permlane32_swap_b32.
// Block = 4 waves x 32 q = 128 queries; KV tile 64; single-buffer LDS,
// register-prefetched staging (T14).
// ---------------------------------------------------------------------------
__global__ __launch_bounds__(256) void attn_mfma32(
    const unsigned short* __restrict__ Q, const unsigned short* __restrict__ K,
    const unsigned short* __restrict__ V, const int* __restrict__ amask,
    unsigned short* __restrict__ AO)
{
    __shared__ unsigned short Ks[64 * 64];   // [kv][d] swizzled
    __shared__ unsigned short Vt[64 * 64];   // [d][kv] swizzled

    const int tid = threadIdx.x;
    const int qb  = (int)gridDim.x - 1 - (int)blockIdx.x;   // big blocks first
    const int n0  = qb * 128;
    const int bh  = blockIdx.y;
    const int b = bh >> 3, h = bh & 7;

    const int lane = tid & 63;
    const int wv   = tid >> 6;
    const int ql   = lane & 31;
    const int hb   = lane >> 5;

    const int qrow  = n0 + 32 * wv + ql;
    const int qminw = n0 + 32 * wv;
    const int qmaxw = qminw + 31;

    // Q fragments (B-operand): lane holds col q=qrow, k(d) = 16*st + 8*hb + j
    bf16x8 qf[4];
    {
        const unsigned short* qp =
            Q + (size_t)(b * SEQ + qrow) * DM + h * DH + 8 * hb;
#pragma unroll
        for (int st = 0; st < 4; ++st)
            qf[st] = *reinterpret_cast<const bf16x8*>(qp + 16 * st);
    }

    f32x16 o[2];
#pragma unroll
    for (int i = 0; i < 16; ++i) { o[0][i] = 0.f; o[1][i] = 0.f; }
    float m_run = NEGINF, l_run = 0.f;   // per lane, for q = qrow (dup across hb)

    int ntiles = (n0 + 127 + WINDOW - 1) / 64 + 1;
    if (ntiles > SEQ / 64) ntiles = SEQ / 64;

    const int r_st = tid & 63;
    const int half = tid >> 6;
    const unsigned short* kpt = K + (size_t)(b * SEQ + r_st) * DM + h * DH + 16 * half;
    const unsigned short* vpt = V + (size_t)(b * SEQ + r_st) * DM + h * DH + 16 * half;
    const int* amp = amask + (size_t)b * SEQ + r_st;

    uint4 kr0, kr1, vr0, vr1; int mr = 1;
    auto issue = [&](int tt) {
        const unsigned short* kp = kpt + (size_t)tt * 64 * DM;
        kr0 = *reinterpret_cast<const uint4*>(kp);
        kr1 = *reinterpret_cast<const uint4*>(kp + 8);
        const unsigned short* vp = vpt + (size_t)tt * 64 * DM;
        vr0 = *reinterpret_cast<const uint4*>(vp);
        vr1 = *reinterpret_cast<const uint4*>(vp + 8);
        mr = amp[tt * 64];
    };
    issue(0);

    for (int t = 0; t < ntiles; ++t) {
        const int kv0 = t * 64;
        __syncthreads();   // previous tile's readers done
        // ---- regs -> LDS ----
        *reinterpret_cast<uint4*>((char*)Ks + swz128(r_st, 32 * half))      = kr0;
        *reinterpret_cast<uint4*>((char*)Ks + swz128(r_st, 32 * half + 16)) = kr1;
        {
            union { uint4 v[2]; unsigned short s[16]; } tv;
            tv.v[0] = vr0; tv.v[1] = vr1;
#pragma unroll
            for (int j = 0; j < 16; ++j)
                *(unsigned short*)((char*)Vt + swz128(16 * half + j, 2 * r_st)) = tv.s[j];
        }
        const unsigned long long mw = __ballot(mr != 0);   // r_st == lane
        __syncthreads();
        if (t + 1 < ntiles) issue(t + 1);   // prefetch hides under compute

        if (kv0 > qmaxw + (WINDOW - 1)) continue;   // wave fully below band

        const bool fullband =
            ((kv0 + 63 - qminw) <= (WINDOW - 1)) && (mw == ~0ULL);

        // ---- S = K Q^T : 2 acc tiles (kv 0-31, 32-63) ----
        f32x16 s[2];
#pragma unroll
        for (int T = 0; T < 2; ++T) {
            f32x16 z;
#pragma unroll
            for (int i = 0; i < 16; ++i) z[i] = 0.f;
#pragma unroll
            for (int st = 0; st < 4; ++st) {
                bf16x8 kf = *reinterpret_cast<const bf16x8*>(
                    (char*)Ks + swz128(32 * T + ql, 32 * st + 16 * hb));
                z = MFMA32(kf, qf[st], z);
            }
            s[T] = z;
        }

        // ---- mask (boundary tiles only); kv = 32T + (rg&3)+8(rg>>2)+4hb ----
        if (!fullband) {
            const int lim = qrow + (WINDOW - 1) - kv0;
#pragma unroll
            for (int T = 0; T < 2; ++T)
#pragma unroll
                for (int rg = 0; rg < 16; ++rg) {
                    const int kvi = 32 * T + (rg & 3) + 8 * (rg >> 2) + 4 * hb;
                    const bool ok = (kvi <= lim) && ((mw >> kvi) & 1ULL);
                    s[T][rg] = ok ? s[T][rg] : NEGINF;
                }
        }

        // ---- lane-local row max (32 values) + cross-half reduce ----
        float tmax = NEGINF;
#pragma unroll
        for (int T = 0; T < 2; ++T)
#pragma unroll
            for (int rg = 0; rg < 16; ++rg) tmax = fmaxf(tmax, s[T][rg]);
        tmax = fmaxf(tmax, __shfl_xor(tmax, 32));
        const float tm2 = tmax * C_SCALE;

        // ---- defer-max rescale (scalar per lane, no shuffles) ----
        if (!__all(tm2 - m_run <= THR2)) {
            const float mn = fmaxf(m_run, tm2);
            const float sc = exp2f(m_run - mn);
            m_run = mn; l_run *= sc;
#pragma unroll
            for (int rg = 0; rg < 16; ++rg) { o[0][rg] *= sc; o[1][rg] *= sc; }
        }

        // ---- P = exp2(s*C - m); pack pairs with v_cvt_pk_bf16_f32 ----
        float ls = 0.f;
        unsigned int pw[16];
#pragma unroll
        for (int T = 0; T < 2; ++T)
#pragma unroll
            for (int i = 0; i < 8; ++i) {
                const float p0 = exp2f(fmaf(s[T][2 * i],     C_SCALE, -m_run));
                const float p1 = exp2f(fmaf(s[T][2 * i + 1], C_SCALE, -m_run));
                ls += p0 + p1;
                unsigned int r;
                asm("v_cvt_pk_bf16_f32 %0, %1, %2" : "=v"(r) : "v"(p0), "v"(p1));
                pw[8 * T + i] = r;
            }
        ls += __shfl_xor(ls, 32);
        l_run += ls;

        // ---- O^T += V^T P : B-frag via one permlane32_swap per word pair ----
#pragma unroll
        for (int c = 0; c < 4; ++c) {
            const int base = 8 * (c >> 1) + 4 * (c & 1);
            unsigned int a0 = pw[base],     b0 = pw[base + 2];
            unsigned int a1 = pw[base + 1], b1 = pw[base + 3];
            asm("v_permlane32_swap_b32 %0, %1" : "+v"(a0), "+v"(b0));
            asm("v_permlane32_swap_b32 %0, %1" : "+v"(a1), "+v"(b1));
            union { unsigned int w[4]; bf16x8 v; } pf;
            pf.w[0] = a0; pf.w[1] = a1; pf.w[2] = b0; pf.w[3] = b1;
#pragma unroll
            for (int dt = 0; dt < 2; ++dt) {
                bf16x8 vf = *reinterpret_cast<const bf16x8*>(
                    (char*)Vt + swz128(32 * dt + ql, 32 * c + 16 * hb));
                o[dt] = MFMA32(vf, pf.v, o[dt]);
            }
        }
    }

    // ---- normalize + store O^T: lane q=qrow, d = (rg&3)+8(rg>>2)+4hb+32dt ----
    const float inv = 1.f / l_run;
    unsigned short* op = AO + (size_t)(b * SEQ + qrow) * DM + h * DH;
#pragma unroll
    for (int dt = 0; dt < 2; ++dt)
#pragma unroll
        for (int p = 0; p < 4; ++p) {
            const float f0 = o[dt][4 * p]     * inv, f1 = o[dt][4 * p + 1] * inv;
            const float f2 = o[dt][4 * p + 2] * inv, f3 = o[dt][4 * p + 3] * inv;
            unsigned int w0, w1;
            asm("v_cvt_pk_bf16_f32 %0, %1, %2" : "=v"(w0) : "v"(f0), "v"(f1));
            asm("v_cvt_pk_bf16_f32 %0, %1, %2" : "=v"(w1) : "v"(f2), "v"(f3));
            uint2 st; st.x = w0; st.y = w1;
            *reinterpret_cast<uint2*>(op + 32 * dt + 8 * p + 4 * hb) = st;
        }
}

extern "C" void kernel_launch(void* const* d_in, const int* in_sizes, int n_in,
                              void* d_out, int out_size, void* d_ws, size_t ws_size,
                              hipStream_t stream) {
    const float* hs    = (const float*)d_in[0];
    const int*   amask = (const int*)  d_in[1];
    const float* Wq    = (const float*)d_in[2];
    const float* Wk    = (const float*)d_in[3];
    const float* Wv    = (const float*)d_in[4];
    const float* Wo    = (const float*)d_in[5];
    float* out = (float*)d_out;

    const size_t tok = (size_t)BATCH * SEQ * DM;
    const size_t wsz = (size_t)DM * DM;
    unsigned short* hsb = (unsigned short*)d_ws;
    unsigned short* Qb  = hsb + tok;
    unsigned short* Kb  = Qb + tok;
    unsigned short* Vb  = Kb + tok;
    unsigned short* AOb = Vb + tok;
    unsigned short* Wb  = AOb + tok;

    const int M = BATCH * SEQ;

    cvt8<<<(int)(tok / 8 / 256), 256, 0, stream>>>(hs, hsb, (int)(tok / 8));
    cvt8_w<<<dim3((int)(wsz / 8 / 256), 4), 256, 0, stream>>>(
        Wq, Wk, Wv, Wo, Wb, (int)(wsz / 8));

    dim3 gQKV(M / 128, DM / 128, 3);
    gemm_mfma<true><<<gQKV, 256, 0, stream>>>(hsb, Wb, Qb, Kb, Vb, M, DM, DM);

    dim3 gAttn(SEQ / 128, BATCH * NH);
    attn_mfma32<<<gAttn, 256, 0, stream>>>(Qb, Kb, Vb, amask, AOb);

    dim3 gOut(M / 128, DM / 128, 1);
    gemm_mfma<false><<<gOut, 256, 0, stream>>>(
        AOb, Wb + 3 * wsz, out, out, out, M, DM, DM);
}